// Round 1
// 242.819 us; speedup vs baseline: 1.1278x; 1.1278x over previous
//
#include <hip/hip_runtime.h>
#include <stdint.h>

// Disable FP contraction file-wide: the d2 <= R2 inclusion test is a discrete
// decision that must match the reference's fp32 mul+add rounding (XLA/numpy do
// not fuse into fma across ops).
#pragma clang fp contract(off)

#define S 256
#define NPTS 100000
#define BATCH 4
#define CCH 64
#define K 8
#define CAP 20   // per-pixel candidate list capacity (lambda~3.4, P(>20)~1e-10)

static constexpr float R2 = 0.01171875f * 0.01171875f;  // (1.5/256*2)^2, exact
static constexpr unsigned long long SENT = 0xFFFFFFFFFFFFFFFFULL;

// ===========================================================================
// NEW PATH: one-atomic append-list scatter + in-blend top-K selection.
// key = (z_bits << 32) | point_idx  -- ascending (z, idx) == reference
// lexsort rank. Scatter no longer maintains sorted order (that was a
// dependent atomicMin cascade, 2-3+ serialized ~400-900cy device-scope
// atomics per candidate, and RMW-bounced the 64B key lines: FETCH+WRITE was
// ~5x buffer size). Now: 1 atomicAdd ticket + 1 plain store per candidate.
// Selection of the 8 smallest keys happens in blend on registers (idle VALU).
// ===========================================================================
__global__ __launch_bounds__(256) void scatter_list_kernel(
        const float* __restrict__ pts,
        unsigned int* __restrict__ counts,
        unsigned long long* __restrict__ lists) {
    int gid = blockIdx.x * blockDim.x + threadIdx.x;
    if (gid >= BATCH * NPTS * 16) return;
    int cell = gid & 15;
    int pid  = gid >> 4;
    int b = pid / NPTS;
    int n = pid - b * NPTS;

    const float* p = pts + (size_t)pid * 3;
    float x = -p[0];                 // reference flips x,y signs
    float y = -p[1];
    float z = p[2];
    if (!(z >= 0.0f)) return;

    float px = (1.0f - x) * 128.0f - 0.5f;   // (1-x)*(S/2) - 0.5
    float py = (1.0f - y) * 128.0f - 0.5f;
    int cj0 = (int)floorf(px);
    int ci0 = (int)floorf(py);

    int ci = ci0 - 1 + (cell >> 2);
    int cj = cj0 - 1 + (cell & 3);
    if (ci < 0 || ci >= S || cj < 0 || cj >= S) return;

    float cy = 1.0f - 2.0f * ((float)ci + 0.5f) / 256.0f;
    float cx = 1.0f - 2.0f * ((float)cj + 0.5f) / 256.0f;
    float dy = cy - y;
    float dx = cx - x;
    float d2 = dy * dy + dx * dx;
    if (!(d2 <= R2)) return;

    unsigned long long key =
        ((unsigned long long)__float_as_uint(z) << 32) | (unsigned int)n;
    size_t base = (size_t)b * (S * S) + (size_t)(ci * S + cj);
    unsigned int old = atomicAdd(&counts[base], 1u);
    if (old < CAP) lists[base * CAP + old] = key;
}

// ---------------------------------------------------------------------------
// Blend for the list path. Block = 256 threads handles (b, row h, 64 pixels).
//   Phase 0: tid<64: read count + up-to-20 keys, partial selection sort in
//            registers -> 8 smallest sorted keys -> LDS. Deterministic:
//            selection over the full (z,idx) key is order-independent.
//   Phase 1: decode keys -> alpha (d2 recomputed from point coords), LDS.
//   Phase 2: exclusive cumprod of (1-alpha) -> weights (tid<64).
//   Phase 3: k-major gather loop, 16 independent gathers in flight per wave.
//   Phase 4: transposed store, one 64B line per lane (4x float4).
// LDS arrays padded to K+1=9 to break the 16-way cumprod bank conflict.
// ---------------------------------------------------------------------------
__global__ __launch_bounds__(256) void blend_list_kernel(
        const float* __restrict__ pts,
        const float* __restrict__ feat,
        const unsigned int* __restrict__ counts,
        const unsigned long long* __restrict__ lists,
        float* __restrict__ out) {
    int seg = blockIdx.x;   // 0..3  (w segment)
    int h   = blockIdx.y;   // 0..255
    int b   = blockIdx.z;   // 0..3
    int tid = threadIdx.x;
    int w0  = seg * 64;

    __shared__ float s_alpha[64][K + 1];
    __shared__ float s_wgt[64][K + 1];
    __shared__ int   s_idx[64][K + 1];
    __shared__ int   s_cnt[64];
    __shared__ unsigned long long s_key[64][K];

    const float* pb = pts + (size_t)b * NPTS * 3;

    // Phase 0: per-pixel top-K selection (one thread per pixel)
    if (tid < 64) {
        size_t base = (size_t)b * (S * S) + (size_t)h * S + (size_t)(w0 + tid);
        int c = (int)counts[base];
        if (c > CAP) c = CAP;
        const ulonglong2* lp2 =
            reinterpret_cast<const ulonglong2*>(lists + base * (size_t)CAP);
        unsigned long long v[CAP];
#pragma unroll
        for (int j = 0; j < CAP / 2; ++j) {
            unsigned long long lo = SENT, hi = SENT;
            if (2 * j < c) { ulonglong2 t = lp2[j]; lo = t.x; hi = t.y; }
            v[2 * j] = lo;
            v[2 * j + 1] = hi;
        }
#pragma unroll
        for (int j = 0; j < CAP; ++j)
            if (j >= c) v[j] = SENT;   // mask garbage beyond count
        // partial selection sort: v[0..7] become the 8 smallest, ascending
#pragma unroll
        for (int i = 0; i < K; ++i) {
#pragma unroll
            for (int j = i + 1; j < CAP; ++j) {
                unsigned long long a = v[i], q = v[j];
                v[i] = a < q ? a : q;
                v[j] = a < q ? q : a;
            }
        }
#pragma unroll
        for (int k = 0; k < K; ++k) s_key[tid][k] = v[k];
        s_cnt[tid] = c < K ? c : K;
    }
    __syncthreads();

    // Phase 1: 512 entries, 2 per thread: decode key -> alpha
    for (int e = tid; e < 64 * K; e += 256) {
        int p = e >> 3;
        int k = e & 7;
        unsigned long long key = s_key[p][k];
        float alpha = 0.0f;
        int idx = 0;
        if (key != SENT) {
            idx = (int)(unsigned int)(key & 0xFFFFFFFFULL);
            float x = -pb[(size_t)idx * 3 + 0];
            float y = -pb[(size_t)idx * 3 + 1];
            int w = w0 + p;
            float cy = 1.0f - 2.0f * ((float)h + 0.5f) / 256.0f;
            float cx = 1.0f - 2.0f * ((float)w + 0.5f) / 256.0f;
            float dy = cy - y;
            float dx = cx - x;
            float d2 = dy * dy + dx * dx;
            float dist = d2 / R2;
            dist = fminf(fmaxf(dist, 0.001f), 1.0f);
            alpha = 1.0f - sqrtf(dist);     // gamma = 1 -> **0.5
        }
        s_alpha[p][k] = alpha;
        s_idx[p][k] = idx;
    }
    __syncthreads();

    // Phase 2: exclusive cumprod of (1 - alpha) -> weights
    if (tid < 64) {
        float t = 1.0f;
#pragma unroll
        for (int k = 0; k < K; ++k) {
            float a = s_alpha[tid][k];      // 0 for invalid slots
            s_wgt[tid][k] = a * t;
            t *= (1.0f - a);
        }
    }
    __syncthreads();

    // Phase 3: k-major accumulate, 16 independent gathers in flight
    int wave = tid >> 6;    // 0..3
    int lane = tid & 63;    // channel
    int pbase = wave * 16;

    int kmax = 0;
#pragma unroll
    for (int i = 0; i < 16; ++i) {
        int c = s_cnt[pbase + i];
        kmax = c > kmax ? c : kmax;
    }

    float acc[16];
#pragma unroll
    for (int i = 0; i < 16; ++i) acc[i] = 0.0f;

    const float* fbl = feat + (size_t)b * NPTS * CCH + lane;
    for (int k = 0; k < kmax; ++k) {
        float v[16];
#pragma unroll
        for (int i = 0; i < 16; ++i) {
            int idx = s_idx[pbase + i][k];          // wave-uniform broadcast
            v[i] = fbl[(size_t)idx << 6];
        }
#pragma unroll
        for (int i = 0; i < 16; ++i) {
            acc[i] += s_wgt[pbase + i][k] * v[i];
        }
    }

    // Phase 4: transposed store, one 64B line per lane (4x float4)
    size_t obase = (((size_t)b * CCH + lane) * S + h) * S + (size_t)(w0 + pbase);
    float4* o4 = (float4*)(out + obase);
#pragma unroll
    for (int q = 0; q < 4; ++q) {
        o4[q] = make_float4(acc[4 * q + 0], acc[4 * q + 1],
                            acc[4 * q + 2], acc[4 * q + 3]);
    }
}

// ===========================================================================
// FALLBACK PATH (unchanged, proven): sorted atomicMin cascade into dense
// per-pixel key slots + original blend. Used only if ws_size is too small
// for the append lists.
// ===========================================================================
__global__ __launch_bounds__(256) void scatter_kernel(
        const float* __restrict__ pts,
        unsigned long long* __restrict__ keys) {
    int gid = blockIdx.x * blockDim.x + threadIdx.x;
    if (gid >= BATCH * NPTS * 16) return;
    int cell = gid & 15;
    int pid  = gid >> 4;
    int b = pid / NPTS;
    int n = pid - b * NPTS;

    const float* p = pts + (size_t)pid * 3;
    float x = -p[0];
    float y = -p[1];
    float z = p[2];
    if (!(z >= 0.0f)) return;

    float px = (1.0f - x) * 128.0f - 0.5f;
    float py = (1.0f - y) * 128.0f - 0.5f;
    int cj0 = (int)floorf(px);
    int ci0 = (int)floorf(py);

    int ci = ci0 - 1 + (cell >> 2);
    int cj = cj0 - 1 + (cell & 3);
    if (ci < 0 || ci >= S || cj < 0 || cj >= S) return;

    float cy = 1.0f - 2.0f * ((float)ci + 0.5f) / 256.0f;
    float cx = 1.0f - 2.0f * ((float)cj + 0.5f) / 256.0f;
    float dy = cy - y;
    float dx = cx - x;
    float d2 = dy * dy + dx * dx;
    if (!(d2 <= R2)) return;

    unsigned long long key =
        ((unsigned long long)__float_as_uint(z) << 32) | (unsigned int)n;
    unsigned long long* slot =
        keys + ((size_t)b * S * S + (size_t)(ci * S + cj)) * K;

    if (slot[K - 1] < key) return;

    for (int s = 0; s < K; ++s) {
        if (key == SENT) break;
        unsigned long long old = atomicMin(&slot[s], key);
        key = old > key ? old : key;
    }
}

__global__ __launch_bounds__(256) void blend_kernel(
        const float* __restrict__ pts,
        const float* __restrict__ feat,
        const unsigned long long* __restrict__ keys,
        float* __restrict__ out) {
    int seg = blockIdx.x;
    int h   = blockIdx.y;
    int b   = blockIdx.z;
    int tid = threadIdx.x;
    int w0  = seg * 64;

    __shared__ float s_alpha[64][K + 1];
    __shared__ float s_wgt[64][K + 1];
    __shared__ int   s_idx[64][K + 1];
    __shared__ int   s_cnt[64];

    const unsigned long long* kb =
        keys + ((size_t)b * S * S + (size_t)h * S + w0) * K;
    const float* pb = pts + (size_t)b * NPTS * 3;

    for (int e = tid; e < 64 * K; e += 256) {
        int p = e >> 3;
        int k = e & 7;
        unsigned long long key = kb[(size_t)p * K + k];
        float alpha = 0.0f;
        int idx = -1;
        if (key != SENT) {
            idx = (int)(unsigned int)(key & 0xFFFFFFFFULL);
            float x = -pb[(size_t)idx * 3 + 0];
            float y = -pb[(size_t)idx * 3 + 1];
            int w = w0 + p;
            float cy = 1.0f - 2.0f * ((float)h + 0.5f) / 256.0f;
            float cx = 1.0f - 2.0f * ((float)w + 0.5f) / 256.0f;
            float dy = cy - y;
            float dx = cx - x;
            float d2 = dy * dy + dx * dx;
            float dist = d2 / R2;
            dist = fminf(fmaxf(dist, 0.001f), 1.0f);
            alpha = 1.0f - sqrtf(dist);
        }
        s_alpha[p][k] = alpha;
        s_idx[p][k] = idx;
    }
    __syncthreads();

    if (tid < 64) {
        float t = 1.0f;
        int cnt = 0;
        for (int k = 0; k < K; ++k) {
            int raw = s_idx[tid][k];
            float a = s_alpha[tid][k];
            s_wgt[tid][k] = a * t;
            t *= (1.0f - a);
            if (raw >= 0) cnt = k + 1;
            s_idx[tid][k] = raw < 0 ? 0 : raw;
        }
        s_cnt[tid] = cnt;
    }
    __syncthreads();

    int wave = tid >> 6;
    int lane = tid & 63;
    int pbase = wave * 16;

    int kmax = 0;
#pragma unroll
    for (int i = 0; i < 16; ++i) {
        int c = s_cnt[pbase + i];
        kmax = c > kmax ? c : kmax;
    }

    float acc[16];
#pragma unroll
    for (int i = 0; i < 16; ++i) acc[i] = 0.0f;

    const float* fbl = feat + (size_t)b * NPTS * CCH + lane;
    for (int k = 0; k < kmax; ++k) {
        float v[16];
#pragma unroll
        for (int i = 0; i < 16; ++i) {
            int idx = s_idx[pbase + i][k];
            v[i] = fbl[(size_t)idx << 6];
        }
#pragma unroll
        for (int i = 0; i < 16; ++i) {
            acc[i] += s_wgt[pbase + i][k] * v[i];
        }
    }

    size_t obase = (((size_t)b * CCH + lane) * S + h) * S + (size_t)(w0 + pbase);
    float4* o4 = (float4*)(out + obase);
#pragma unroll
    for (int q = 0; q < 4; ++q) {
        o4[q] = make_float4(acc[4 * q + 0], acc[4 * q + 1],
                            acc[4 * q + 2], acc[4 * q + 3]);
    }
}

extern "C" void kernel_launch(void* const* d_in, const int* in_sizes, int n_in,
                              void* d_out, int out_size, void* d_ws, size_t ws_size,
                              hipStream_t stream) {
    const float* pts  = (const float*)d_in[0];
    const float* feat = (const float*)d_in[1];
    float* out = (float*)d_out;

    size_t cnt_bytes  = (size_t)BATCH * S * S * sizeof(unsigned int);      // 1 MB
    size_t list_bytes = (size_t)BATCH * S * S * CAP * sizeof(unsigned long long); // 42 MB

    if (ws_size >= cnt_bytes + list_bytes) {
        // list path: 1-atomic commit, top-K selection deferred to blend
        unsigned int* counts = (unsigned int*)d_ws;
        unsigned long long* lists =
            (unsigned long long*)((char*)d_ws + cnt_bytes);
        hipMemsetAsync(counts, 0, cnt_bytes, stream);

        int total = BATCH * NPTS * 16;
        scatter_list_kernel<<<(total + 255) / 256, 256, 0, stream>>>(
            pts, counts, lists);

        dim3 grid(S / 64, S, BATCH);
        blend_list_kernel<<<grid, 256, 0, stream>>>(pts, feat, counts, lists, out);
    } else {
        // fallback: proven sorted-cascade path
        unsigned long long* keys = (unsigned long long*)d_ws;
        size_t key_bytes = (size_t)BATCH * S * S * K * sizeof(unsigned long long);
        hipMemsetAsync(keys, 0xFF, key_bytes, stream);

        int total = BATCH * NPTS * 16;
        scatter_kernel<<<(total + 255) / 256, 256, 0, stream>>>(pts, keys);

        dim3 grid(S / 64, S, BATCH);
        blend_kernel<<<grid, 256, 0, stream>>>(pts, feat, keys, out);
    }
}